// Round 11
// baseline (150.102 us; speedup 1.0000x reference)
//
#include <hip/hip_runtime.h>
#include <stdint.h>

// Problem constants (fixed by reference setup_inputs)
#define NPOS 512   // N
#define NH   64    // H
#define NM   1024  // M
#define NB   256   // B
#define NM1  511   // N-1
#define LDW  66    // LDS row stride (shorts): odd dword count -> conflict-free b128 reads

typedef __attribute__((ext_vector_type(8)))  short bf16x8;
typedef __attribute__((ext_vector_type(16))) float f32x16;
typedef __attribute__((ext_vector_type(4)))  float f32x4;
typedef __attribute__((ext_vector_type(4)))  int   i32x4;

#if __has_builtin(__builtin_amdgcn_exp2f)
#define EXP2F(x) __builtin_amdgcn_exp2f(x)
#else
#define EXP2F(x) __expf((x) * 0.69314718055994531f)
#endif

__device__ __forceinline__ unsigned short f2bf(float x) {
    unsigned u = __float_as_uint(x);
    u = (u + 0x7FFFu + ((u >> 16) & 1u)) >> 16;   // RNE
    return (unsigned short)u;
}
__device__ __forceinline__ int pack2(unsigned short a, unsigned short b) {
    return (int)a | ((int)b << 16);
}
// v_cvt_pk_bf16_f32: two f32 -> packed 2x bf16 (low=s0, high=s1)
__device__ __forceinline__ int cvtpk(float lo, float hi) {
    int r;
    asm volatile("v_cvt_pk_bf16_f32 %0, %1, %2" : "=v"(r) : "v"(lo), "v"(hi));
    return r;
}

// ---------------- kA: fused prep = {k0 seq->bf16 + zero out, k1a BnT softmax,
//                  k1c plusT transpose}. 272 blocks x 256 thr. (R0, proven) ---
__global__ __launch_bounds__(256, 4)
void kA_prep(const float* __restrict__ seq, const float* __restrict__ Bl,
             const float* __restrict__ mem,
             unsigned short* __restrict__ seq_bf, float* __restrict__ BnT,
             float* __restrict__ plusT, float* __restrict__ out) {
    const int bid = blockIdx.x, t = threadIdx.x;
    if (bid < 128) {
        // --- k0: sequences fp32 -> bf16 (exact for +/-1) ---
        if (bid == 0 && t == 0) out[0] = 0.f;
        int idx = (bid * 256 + t) * 4;
        f32x4 v = *(const f32x4*)(seq + idx);
        int2 o;
        o.x = pack2(f2bf(v.x), f2bf(v.y));
        o.y = pack2(f2bf(v.z), f2bf(v.w));
        *(int2*)(seq_bf + idx) = o;
    } else if (bid < 144) {
        // --- k1a: Bn = softmax(B_logits, axis=-1), stored transposed ---
        const int h = (bid - 128) * 4 + (t >> 6), l = t & 63;
        float v[8]; float mx = -1e30f;
#pragma unroll
        for (int j = 0; j < 8; j++) { v[j] = Bl[h * NPOS + l + 64 * j]; mx = fmaxf(mx, v[j]); }
#pragma unroll
        for (int o = 32; o; o >>= 1) mx = fmaxf(mx, __shfl_xor(mx, o));
        float s = 0.f;
#pragma unroll
        for (int j = 0; j < 8; j++) { v[j] = __expf(v[j] - mx); s += v[j]; }
#pragma unroll
        for (int o = 32; o; o >>= 1) s += __shfl_xor(s, o);
        float r = 1.0f / s;
#pragma unroll
        for (int j = 0; j < 8; j++) BnT[(l + 64 * j) * NH + h] = v[j] * r;
    } else {
        // --- k1c: plusT[n][m] via LDS 64x64 tile transpose ---
        __shared__ float sT[64][65];
        const int bb = bid - 144;
        const int mt = bb >> 3, nt = bb & 7;
        const int rr = t >> 2, cc = t & 3;
        const float* src = mem + (size_t)(mt * 64 + rr) * NPOS + nt * 64 + cc * 16;
#pragma unroll
        for (int j = 0; j < 4; j++) {
            f32x4 v = *(const f32x4*)(src + j * 4);
            sT[rr][cc * 16 + j * 4 + 0] = (v.x > 0.f) ? 1.f : 0.f;
            sT[rr][cc * 16 + j * 4 + 1] = (v.y > 0.f) ? 1.f : 0.f;
            sT[rr][cc * 16 + j * 4 + 2] = (v.z > 0.f) ? 1.f : 0.f;
            sT[rr][cc * 16 + j * 4 + 3] = (v.w > 0.f) ? 1.f : 0.f;
        }
        __syncthreads();
        float* dst = plusT + (size_t)(nt * 64 + rr) * NM + mt * 64 + cc * 16;
#pragma unroll
        for (int j = 0; j < 4; j++) {
            f32x4 o;
            o.x = sT[cc * 16 + j * 4 + 0][rr];
            o.y = sT[cc * 16 + j * 4 + 1][rr];
            o.z = sT[cc * 16 + j * 4 + 2][rr];
            o.w = sT[cc * 16 + j * 4 + 3][rr];
            *(f32x4*)(dst + j * 4) = o;
        }
    }
}

// ---------------- k1b: phi_mu[m,h] -> bf16 FRAGMENT layout only --------------
// 128 blocks x 8 m-rows. PRE-SCALED by log2(e).
__global__ __launch_bounds__(256, 4)
void k1b_phimu(const float* __restrict__ BnT, const float* __restrict__ mem,
               unsigned short* __restrict__ phimuF) {
    const int m0 = blockIdx.x * 8, t = threadIdx.x;
    __shared__ float mrow[8][NPOS];   // 16 KB
    __shared__ float part[8][256];    // 8 KB
#pragma unroll
    for (int ch = 0; ch < 4; ch++) {
        int idx = ch * 256 + t;
        int row = idx >> 7, col = (idx & 127) * 4;
        *(f32x4*)(&mrow[row][col]) = *(const f32x4*)(mem + (size_t)(m0 + row) * NPOS + col);
    }
    __syncthreads();
    const int h = t & 63, seg = t >> 6;
    float a[8], b2[8];
#pragma unroll
    for (int row = 0; row < 8; row++) { a[row] = 0.f; b2[row] = 0.f; }
    const float* bp = BnT + seg * 128 * NH + h;
#pragma unroll 4
    for (int nn = 0; nn < 128; nn += 2) {
        float x0 = bp[nn * NH], x1 = bp[(nn + 1) * NH];
#pragma unroll
        for (int row = 0; row < 8; row++) {
            a[row]  = fmaf(x0, mrow[row][seg * 128 + nn], a[row]);
            b2[row] = fmaf(x1, mrow[row][seg * 128 + nn + 1], b2[row]);
        }
    }
#pragma unroll
    for (int row = 0; row < 8; row++) part[row][t] = a[row] + b2[row];
    __syncthreads();
    if (t < 64) {
#pragma unroll
        for (int row = 0; row < 8; row++) {
            float s = (part[row][t] + part[row][t + 64]) + (part[row][t + 128] + part[row][t + 192]);
            unsigned short v = f2bf(s * 1.4426950408889634f);   // * log2(e)
            const int m = m0 + row;
            const int tile = m >> 5, rr = m & 31;
            const int kq = t >> 4, hi2 = (t >> 3) & 1, j = t & 7;
            phimuF[(size_t)((tile * 4 + kq) * 64 + rr + 32 * hi2) * 8 + j] = v;
        }
    }
}

// ------------- phase-2 helper: coalesced fragment load (R8, proven) ----------
__device__ __forceinline__ void p2_loadF(bf16x8 (&p)[4], const unsigned short* __restrict__ phimuF,
                                         int tile, int lane) {
#pragma unroll
    for (int kq = 0; kq < 4; kq++)
        p[kq] = *(const bf16x8*)(phimuF + (size_t)((tile * 4 + kq) * 64 + lane) * 8);
}

// ---------------- k23: FUSED hat_phi + retrieval softmax + BCE ---------------
// grid 511, 256 thr = 4 waves. Changes vs R9 (champion, 46.7us):
//  * big/small n pairing restored (R5): bid even -> n=511-c, odd -> n=1+c
//    -> ~uniform phase-1 ksteps per CU (kills the straggler tail).
//  * LDS stride 72 -> 66 shorts (odd dword count): every ds_read_b128 in both
//    phases conflict-free (was 4-way aliased; SQ_LDS_BANK_CONFLICT=32704).
//  * W via per-lane LDS address (lane0 -> ones row, lane1 -> walking plus
//    pointer, lanes 2-31 -> zeros row): deletes 16 mask-VALU/iter; W register
//    values bitwise identical to R9.
//  * R10's software pipelining reverted (measured neutral-negative).
__global__ __launch_bounds__(256, 2)
void k23_fused(const float* __restrict__ Al, const unsigned short* __restrict__ seq_bf,
               const unsigned short* __restrict__ phimuF, const float* __restrict__ plusT,
               const float* __restrict__ seq, float* __restrict__ out) {
    __shared__ __align__(16) unsigned short e_lds[2][64 * LDW];  // E dbuf -> dsum/nsum scratch
    __shared__ __align__(16) unsigned short q_lds[256 * LDW];    // q tile
    __shared__ __align__(16) unsigned short plusbf[1040];        // W table + ones(1024) + zeros(1032)
    __shared__ float z_lds[64];                                  // row sums Z[h]
    __shared__ float w_lds[4];

    const int t = threadIdx.x;
    const int c0 = blockIdx.x >> 1;
    const int n = (blockIdx.x & 1) ? (1 + c0) : (NM1 - c0);      // big/small pairing
    const int ksteps = (n + 63) >> 6;
    const int wv = t >> 6, lane = t & 63, half = lane >> 5, r = lane & 31;

    if (t < 64) z_lds[t] = 0.f;
    // W table from plusT: entry (tile, mm, hh) = plus[n][tile*32+mm*16+hh*4 +
    // {0..3}] ++ [+8..+11] (k-order sigma of the reduce-MFMA A-fragment)
    if (t < 128) {
        const int tile = t >> 2, mm = (t >> 1) & 1, hh = t & 1;
        const float* src = plusT + (size_t)n * NM + tile * 32 + mm * 16 + hh * 4;
        f32x4 v0 = *(const f32x4*)(src);
        f32x4 v1 = *(const f32x4*)(src + 8);
        unsigned short* dst = plusbf + (size_t)((tile * 2 + mm) * 2 + hh) * 8;
        dst[0] = f2bf(v0.x); dst[1] = f2bf(v0.y); dst[2] = f2bf(v0.z); dst[3] = f2bf(v0.w);
        dst[4] = f2bf(v1.x); dst[5] = f2bf(v1.y); dst[6] = f2bf(v1.z); dst[7] = f2bf(v1.w);
    } else if (t == 128) {
        // ones / zeros rows for the per-lane W addressing
#pragma unroll
        for (int j = 0; j < 8; j++) { plusbf[1024 + j] = 0x3F80; plusbf[1032 + j] = 0; }
    }

    // ================= phase 1: hat_phi tile (256 b x 64 h) =================
    const int eh = t >> 2, ei = (t & 3) * 16;
    const float* arow = Al + ((size_t)n * NH + eh) * NPOS + ei;
    const unsigned short* s0 = seq_bf + (size_t)(wv * 64 + r) * NPOS;        // bs=0
    const unsigned short* s1 = seq_bf + (size_t)(wv * 64 + 32 + r) * NPOS;   // bs=1

    f32x16 acc00, acc01, acc10, acc11;
#pragma unroll
    for (int i = 0; i < 16; i++) { acc00[i] = 0.f; acc01[i] = 0.f; acc10[i] = 0.f; acc11[i] = 0.f; }

    f32x4 ea[4];
    bf16x8 sc0[4], sc1[4], sn0[4], sn1[4];
#pragma unroll
    for (int g = 0; g < 4; g++) ea[g] = *(const f32x4*)(arow + g * 4);
#pragma unroll
    for (int kq = 0; kq < 4; kq++) {
        sc0[kq] = *(const bf16x8*)(s0 + kq * 16 + half * 8);
        sc1[kq] = *(const bf16x8*)(s1 + kq * 16 + half * 8);
    }
    __syncthreads();   // z_lds init + W table staged

    for (int kk = 0; kk < ksteps; kk++) {
        const int k0 = kk * 64;
        unsigned short* ebuf = (unsigned short*)e_lds[kk & 1];
        // 1. exp + stage E tile from regs (masked), accumulate Z
        {
            float zp = 0.f;
            unsigned short* ep = ebuf + eh * LDW + ei;
#pragma unroll
            for (int g = 0; g < 4; g++) {
                int i0 = k0 + ei + g * 4;
                float e0 = (i0 + 0 < n) ? __expf(ea[g].x) : 0.f;
                float e1 = (i0 + 1 < n) ? __expf(ea[g].y) : 0.f;
                float e2 = (i0 + 2 < n) ? __expf(ea[g].z) : 0.f;
                float e3 = (i0 + 3 < n) ? __expf(ea[g].w) : 0.f;
                zp += (e0 + e1) + (e2 + e3);
                int2 o; o.x = pack2(f2bf(e0), f2bf(e1)); o.y = pack2(f2bf(e2), f2bf(e3));
                *(int2*)(ep + g * 4) = o;
            }
            zp += __shfl_xor(zp, 1);
            zp += __shfl_xor(zp, 2);
            if ((t & 3) == 0) z_lds[eh] += zp;
        }
        // 2. prefetch k+1 (A row + S fragments) — stays in flight across barrier
        if (kk + 1 < ksteps) {
#pragma unroll
            for (int g = 0; g < 4; g++) ea[g] = *(const f32x4*)(arow + k0 + 64 + g * 4);
#pragma unroll
            for (int kq = 0; kq < 4; kq++) {
                sn0[kq] = *(const bf16x8*)(s0 + k0 + 64 + kq * 16 + half * 8);
                sn1[kq] = *(const bf16x8*)(s1 + k0 + 64 + kq * 16 + half * 8);
            }
        }
        // 3. LDS-only fence + raw barrier (global prefetches NOT drained)
        asm volatile("s_waitcnt lgkmcnt(0)" ::: "memory");
        __builtin_amdgcn_s_barrier();
        asm volatile("" ::: "memory");
        // 4. MFMA: D[b][h] += S[b,i] * E[h,i]
        {
            const unsigned short* sB0 = ebuf + r * LDW;
            const unsigned short* sB1 = sB0 + 32 * LDW;
#pragma unroll
            for (int kq = 0; kq < 4; kq++) {
                const int ko = kq * 16 + half * 8;
                bf16x8 B0 = *(const bf16x8*)(sB0 + ko);
                bf16x8 B1 = *(const bf16x8*)(sB1 + ko);
                acc00 = __builtin_amdgcn_mfma_f32_32x32x16_bf16(sc0[kq], B0, acc00, 0, 0, 0);
                acc01 = __builtin_amdgcn_mfma_f32_32x32x16_bf16(sc0[kq], B1, acc01, 0, 0, 0);
                acc10 = __builtin_amdgcn_mfma_f32_32x32x16_bf16(sc1[kq], B0, acc10, 0, 0, 0);
                acc11 = __builtin_amdgcn_mfma_f32_32x32x16_bf16(sc1[kq], B1, acc11, 0, 0, 0);
            }
        }
        // 5. rotate S fragments
        if (kk + 1 < ksteps) {
#pragma unroll
            for (int kq = 0; kq < 4; kq++) { sc0[kq] = sn0[kq]; sc1[kq] = sn1[kq]; }
        }
    }
    // epilogue: scale by 1/Z[h], write q tile into q_lds (wave-own rows; no
    // barrier needed before the same wave reads them back in phase 2).
    {
        float rz0 = 1.0f / z_lds[r];
        float rz1 = 1.0f / z_lds[32 + r];
#pragma unroll
        for (int reg = 0; reg < 16; reg++) {
            int row = (reg & 3) + 8 * (reg >> 2) + 4 * half;
            q_lds[(wv * 64 + row) * LDW + r]            = f2bf(acc00[reg] * rz0);
            q_lds[(wv * 64 + row) * LDW + 32 + r]       = f2bf(acc01[reg] * rz1);
            q_lds[(wv * 64 + 32 + row) * LDW + r]       = f2bf(acc10[reg] * rz0);
            q_lds[(wv * 64 + 32 + row) * LDW + 32 + r]  = f2bf(acc11[reg] * rz1);
        }
    }

    // ================= phase 2: retrieval softmax (MFMA-reduced) ============
    bf16x8 p[4], pn[4];
    p2_loadF(p, phimuF, 0, lane);              // coalesced; issue first
    bf16x8 q0[4], q1[4];
#pragma unroll
    for (int kq = 0; kq < 4; kq++) {
        q0[kq] = *(const bf16x8*)(q_lds + (wv * 64 + r) * LDW + kq * 16 + half * 8);
        q1[kq] = *(const bf16x8*)(q_lds + (wv * 64 + 32 + r) * LDW + kq * 16 + half * 8);
    }
    f32x16 zacc, accD0, accD1;
#pragma unroll
    for (int i = 0; i < 16; i++) { zacc[i] = 0.f; accD0[i] = 0.f; accD1[i] = 0.f; }

    // per-lane W source: lane 0 -> ones row, lane 1 -> walking plus pointer,
    // lanes 2..31 -> zeros row. Register values identical to the old VALU mask.
    const unsigned short* wb1 = (r == 1) ? (plusbf + half * 8)
                              : (r == 0) ? (plusbf + 1024) : (plusbf + 1032);
    const unsigned short* wb2 = (r == 1) ? (plusbf + (2 + half) * 8)
                              : (r == 0) ? (plusbf + 1024) : (plusbf + 1032);
    const int wstep = (r == 1) ? 32 : 0;       // shorts per tile (4 slots x 8)

    for (int it = 0; it < 32; ++it) {
        if (it < 31) p2_loadF(pn, phimuF, it + 1, lane);   // prefetch, no barrier
        // score MFMAs: a0 (b 0..31), a1 (b 32..63)
        f32x16 a0, a1;
        a0 = __builtin_amdgcn_mfma_f32_32x32x16_bf16(p[0], q0[0], zacc, 0, 0, 0);
        a1 = __builtin_amdgcn_mfma_f32_32x32x16_bf16(p[0], q1[0], zacc, 0, 0, 0);
#pragma unroll
        for (int kq = 1; kq < 4; kq++) {
            a0 = __builtin_amdgcn_mfma_f32_32x32x16_bf16(p[kq], q0[kq], a0, 0, 0, 0);
            a1 = __builtin_amdgcn_mfma_f32_32x32x16_bf16(p[kq], q1[kq], a1, 0, 0, 0);
        }
        // W fragments for this tile via per-lane addresses (no mask VALU)
        i32x4 W1 = *(const i32x4*)wb1;
        i32x4 W2 = *(const i32x4*)wb2;
        wb1 += wstep; wb2 += wstep;
        // exp -> bf16 A-fragments, reduce-MFMA into accD (col0=den, col1=num)
        {
            float e00 = EXP2F(a0[0]),  e01 = EXP2F(a0[1]),  e02 = EXP2F(a0[2]),  e03 = EXP2F(a0[3]);
            float e04 = EXP2F(a0[4]),  e05 = EXP2F(a0[5]),  e06 = EXP2F(a0[6]),  e07 = EXP2F(a0[7]);
            float e08 = EXP2F(a0[8]),  e09 = EXP2F(a0[9]),  e10 = EXP2F(a0[10]), e11 = EXP2F(a0[11]);
            float e12 = EXP2F(a0[12]), e13 = EXP2F(a0[13]), e14 = EXP2F(a0[14]), e15 = EXP2F(a0[15]);
            i32x4 A1, A2;
            A1.x = cvtpk(e00, e01); A1.y = cvtpk(e02, e03); A1.z = cvtpk(e04, e05); A1.w = cvtpk(e06, e07);
            A2.x = cvtpk(e08, e09); A2.y = cvtpk(e10, e11); A2.z = cvtpk(e12, e13); A2.w = cvtpk(e14, e15);
            accD0 = __builtin_amdgcn_mfma_f32_32x32x16_bf16(*(bf16x8*)&A1, *(bf16x8*)&W1, accD0, 0, 0, 0);
            accD0 = __builtin_amdgcn_mfma_f32_32x32x16_bf16(*(bf16x8*)&A2, *(bf16x8*)&W2, accD0, 0, 0, 0);
        }
        {
            float e00 = EXP2F(a1[0]),  e01 = EXP2F(a1[1]),  e02 = EXP2F(a1[2]),  e03 = EXP2F(a1[3]);
            float e04 = EXP2F(a1[4]),  e05 = EXP2F(a1[5]),  e06 = EXP2F(a1[6]),  e07 = EXP2F(a1[7]);
            float e08 = EXP2F(a1[8]),  e09 = EXP2F(a1[9]),  e10 = EXP2F(a1[10]), e11 = EXP2F(a1[11]);
            float e12 = EXP2F(a1[12]), e13 = EXP2F(a1[13]), e14 = EXP2F(a1[14]), e15 = EXP2F(a1[15]);
            i32x4 A1, A2;
            A1.x = cvtpk(e00, e01); A1.y = cvtpk(e02, e03); A1.z = cvtpk(e04, e05); A1.w = cvtpk(e06, e07);
            A2.x = cvtpk(e08, e09); A2.y = cvtpk(e10, e11); A2.z = cvtpk(e12, e13); A2.w = cvtpk(e14, e15);
            accD1 = __builtin_amdgcn_mfma_f32_32x32x16_bf16(*(bf16x8*)&A1, *(bf16x8*)&W1, accD1, 0, 0, 0);
            accD1 = __builtin_amdgcn_mfma_f32_32x32x16_bf16(*(bf16x8*)&A2, *(bf16x8*)&W2, accD1, 0, 0, 0);
        }
        if (it < 31) {
#pragma unroll
            for (int kq = 0; kq < 4; kq++) p[kq] = pn[kq];
        }
    }

    // formal fence: all waves done reading e_lds (phase 1) before reuse below
    __syncthreads();
    // accD layout: col r==0 holds den[b=rowmap], col r==1 holds num.
    float* dsum = (float*)e_lds;          // 256 floats (e_lds dead after phase 1)
    float* nsum = dsum + 256;
    if (r < 2) {
        float* dst = (r == 0) ? dsum : nsum;
#pragma unroll
        for (int reg = 0; reg < 16; reg++) {
            int row = (reg & 3) + 8 * (reg >> 2) + 4 * half;
            dst[wv * 64 + row]      = accD0[reg];
            dst[wv * 64 + 32 + row] = accD1[reg];
        }
    }
    __syncthreads();
    // BCE for b = t
    {
        float dd = dsum[t], nn = nsum[t];
        float p2 = nn / dd;
        p2 = fminf(fmaxf(p2, 1e-6f), 1.0f - 1e-6f);
        float tg = seq[(size_t)t * NPOS + n];
        float bce = (tg > 0.f) ? -logf(p2) : -logf(1.0f - p2);
#pragma unroll
        for (int o = 32; o; o >>= 1) bce += __shfl_xor(bce, o);
        if (lane == 0) w_lds[wv] = bce;
    }
    __syncthreads();
    if (t == 0)
        atomicAdd(out, (w_lds[0] + w_lds[1] + w_lds[2] + w_lds[3]) * (1.0f / 130816.0f));
}

extern "C" void kernel_launch(void* const* d_in, const int* in_sizes, int n_in,
                              void* d_out, int out_size, void* d_ws, size_t ws_size,
                              hipStream_t stream) {
    const float* seq = (const float*)d_in[0];  // (B,N)
    const float* mem = (const float*)d_in[1];  // (M,N)
    const float* Al  = (const float*)d_in[2];  // (N,H,N)
    const float* Bl  = (const float*)d_in[3];  // (H,N)

    char* ws = (char*)d_ws;
    unsigned short* seq_bf = (unsigned short*)(ws + 0);          // 256 KB
    float*          BnT    = (float*)(ws + 262144);              // 128 KB (N,H)
    unsigned short* phimuF = (unsigned short*)(ws + 393216);     // 128 KB fragment layout
    float*          plusT  = (float*)(ws + 524288);              // 2 MB (N,M)
    float*          outp   = (float*)d_out;                      // total 2.6 MB (proven R0-R3)

    kA_prep<<<272, 256, 0, stream>>>(seq, Bl, mem, seq_bf, BnT, plusT, outp);
    k1b_phimu<<<128, 256, 0, stream>>>(BnT, mem, phimuF);
    k23_fused<<<511, 256, 0, stream>>>(Al, seq_bf, phimuF, plusT, seq, outp);
}

// Round 13
// 140.409 us; speedup vs baseline: 1.0690x; 1.0690x over previous
//
#include <hip/hip_runtime.h>
#include <stdint.h>

// Problem constants (fixed by reference setup_inputs)
#define NPOS 512   // N
#define NH   64    // H
#define NM   1024  // M
#define NB   256   // B
#define NM1  511   // N-1

typedef __attribute__((ext_vector_type(8)))  short bf16x8;
typedef __attribute__((ext_vector_type(16))) float f32x16;
typedef __attribute__((ext_vector_type(4)))  float f32x4;
typedef __attribute__((ext_vector_type(4)))  int   i32x4;

#if __has_builtin(__builtin_amdgcn_exp2f)
#define EXP2F(x) __builtin_amdgcn_exp2f(x)
#else
#define EXP2F(x) __expf((x) * 0.69314718055994531f)
#endif

__device__ __forceinline__ unsigned short f2bf(float x) {
    unsigned u = __float_as_uint(x);
    u = (u + 0x7FFFu + ((u >> 16) & 1u)) >> 16;   // RNE
    return (unsigned short)u;
}
__device__ __forceinline__ int pack2(unsigned short a, unsigned short b) {
    return (int)a | ((int)b << 16);
}
// v_cvt_pk_bf16_f32: two f32 -> packed 2x bf16 (low=s0, high=s1)
__device__ __forceinline__ int cvtpk(float lo, float hi) {
    int r;
    asm volatile("v_cvt_pk_bf16_f32 %0, %1, %2" : "=v"(r) : "v"(lo), "v"(hi));
    return r;
}

// ---------------- kA: fused prep = {k0 seq->bf16 + zero out, k1a BnT softmax,
//                  k1c plusT transpose}. 272 blocks x 256 thr. (R0, proven) ---
__global__ __launch_bounds__(256, 4)
void kA_prep(const float* __restrict__ seq, const float* __restrict__ Bl,
             const float* __restrict__ mem,
             unsigned short* __restrict__ seq_bf, float* __restrict__ BnT,
             float* __restrict__ plusT, float* __restrict__ out) {
    const int bid = blockIdx.x, t = threadIdx.x;
    if (bid < 128) {
        // --- k0: sequences fp32 -> bf16 (exact for +/-1) ---
        if (bid == 0 && t == 0) out[0] = 0.f;
        int idx = (bid * 256 + t) * 4;
        f32x4 v = *(const f32x4*)(seq + idx);
        int2 o;
        o.x = pack2(f2bf(v.x), f2bf(v.y));
        o.y = pack2(f2bf(v.z), f2bf(v.w));
        *(int2*)(seq_bf + idx) = o;
    } else if (bid < 144) {
        // --- k1a: Bn = softmax(B_logits, axis=-1), stored transposed ---
        const int h = (bid - 128) * 4 + (t >> 6), l = t & 63;
        float v[8]; float mx = -1e30f;
#pragma unroll
        for (int j = 0; j < 8; j++) { v[j] = Bl[h * NPOS + l + 64 * j]; mx = fmaxf(mx, v[j]); }
#pragma unroll
        for (int o = 32; o; o >>= 1) mx = fmaxf(mx, __shfl_xor(mx, o));
        float s = 0.f;
#pragma unroll
        for (int j = 0; j < 8; j++) { v[j] = __expf(v[j] - mx); s += v[j]; }
#pragma unroll
        for (int o = 32; o; o >>= 1) s += __shfl_xor(s, o);
        float r = 1.0f / s;
#pragma unroll
        for (int j = 0; j < 8; j++) BnT[(l + 64 * j) * NH + h] = v[j] * r;
    } else {
        // --- k1c: plusT[n][m] via LDS 64x64 tile transpose ---
        __shared__ float sT[64][65];
        const int bb = bid - 144;
        const int mt = bb >> 3, nt = bb & 7;
        const int rr = t >> 2, cc = t & 3;
        const float* src = mem + (size_t)(mt * 64 + rr) * NPOS + nt * 64 + cc * 16;
#pragma unroll
        for (int j = 0; j < 4; j++) {
            f32x4 v = *(const f32x4*)(src + j * 4);
            sT[rr][cc * 16 + j * 4 + 0] = (v.x > 0.f) ? 1.f : 0.f;
            sT[rr][cc * 16 + j * 4 + 1] = (v.y > 0.f) ? 1.f : 0.f;
            sT[rr][cc * 16 + j * 4 + 2] = (v.z > 0.f) ? 1.f : 0.f;
            sT[rr][cc * 16 + j * 4 + 3] = (v.w > 0.f) ? 1.f : 0.f;
        }
        __syncthreads();
        float* dst = plusT + (size_t)(nt * 64 + rr) * NM + mt * 64 + cc * 16;
#pragma unroll
        for (int j = 0; j < 4; j++) {
            f32x4 o;
            o.x = sT[cc * 16 + j * 4 + 0][rr];
            o.y = sT[cc * 16 + j * 4 + 1][rr];
            o.z = sT[cc * 16 + j * 4 + 2][rr];
            o.w = sT[cc * 16 + j * 4 + 3][rr];
            *(f32x4*)(dst + j * 4) = o;
        }
    }
}

// ---------------- k1b: phi_mu[m,h] -> bf16 FRAGMENT layout only --------------
// 128 blocks x 8 m-rows. PRE-SCALED by log2(e).
__global__ __launch_bounds__(256, 4)
void k1b_phimu(const float* __restrict__ BnT, const float* __restrict__ mem,
               unsigned short* __restrict__ phimuF) {
    const int m0 = blockIdx.x * 8, t = threadIdx.x;
    __shared__ float mrow[8][NPOS];   // 16 KB
    __shared__ float part[8][256];    // 8 KB
#pragma unroll
    for (int ch = 0; ch < 4; ch++) {
        int idx = ch * 256 + t;
        int row = idx >> 7, col = (idx & 127) * 4;
        *(f32x4*)(&mrow[row][col]) = *(const f32x4*)(mem + (size_t)(m0 + row) * NPOS + col);
    }
    __syncthreads();
    const int h = t & 63, seg = t >> 6;
    float a[8], b2[8];
#pragma unroll
    for (int row = 0; row < 8; row++) { a[row] = 0.f; b2[row] = 0.f; }
    const float* bp = BnT + seg * 128 * NH + h;
#pragma unroll 4
    for (int nn = 0; nn < 128; nn += 2) {
        float x0 = bp[nn * NH], x1 = bp[(nn + 1) * NH];
#pragma unroll
        for (int row = 0; row < 8; row++) {
            a[row]  = fmaf(x0, mrow[row][seg * 128 + nn], a[row]);
            b2[row] = fmaf(x1, mrow[row][seg * 128 + nn + 1], b2[row]);
        }
    }
#pragma unroll
    for (int row = 0; row < 8; row++) part[row][t] = a[row] + b2[row];
    __syncthreads();
    if (t < 64) {
#pragma unroll
        for (int row = 0; row < 8; row++) {
            float s = (part[row][t] + part[row][t + 64]) + (part[row][t + 128] + part[row][t + 192]);
            unsigned short v = f2bf(s * 1.4426950408889634f);   // * log2(e)
            const int m = m0 + row;
            const int tile = m >> 5, rr = m & 31;
            const int kq = t >> 4, hi2 = (t >> 3) & 1, j = t & 7;
            phimuF[(size_t)((tile * 4 + kq) * 64 + rr + 32 * hi2) * 8 + j] = v;
        }
    }
}

// ------------- phase-2 helper: coalesced fragment load (R8, proven) ----------
__device__ __forceinline__ void p2_loadF(bf16x8 (&p)[4], const unsigned short* __restrict__ phimuF,
                                         int tile, int lane) {
#pragma unroll
    for (int kq = 0; kq < 4; kq++)
        p[kq] = *(const bf16x8*)(phimuF + (size_t)((tile * 4 + kq) * 64 + lane) * 8);
}

// ---------------- k23: FUSED hat_phi + retrieval softmax + BCE ---------------
// grid 511, 256 thr = 4 waves. EXACT R9 champion (46.7us) with ONE change:
// CU-aware n pairing. Blocks bid and bid+256 co-reside on the same CU
// (round-robin XCD mapping), so map n = (bid<256) ? 511-bid : bid-255 —
// co-resident pairs sum to 512 -> ~9 ksteps/CU uniformly (R9 worst CU: 12).
// R10 pipelining and R11 stride/W changes reverted (measured regressions).
// (R12 run of this exact source died to container infra; resubmitted as-is.)
__global__ __launch_bounds__(256, 2)
void k23_fused(const float* __restrict__ Al, const unsigned short* __restrict__ seq_bf,
               const unsigned short* __restrict__ phimuF, const float* __restrict__ plusT,
               const float* __restrict__ seq, float* __restrict__ out) {
    __shared__ __align__(16) unsigned short e_lds[2][64 * 72];   // E dbuf -> dsum/nsum scratch
    __shared__ __align__(16) unsigned short q_lds[256 * 72];     // q tile (36864 B)
    __shared__ __align__(16) unsigned short plusbf[32 * 2 * 2 * 8]; // W table (2 KB)
    __shared__ float z_lds[64];                                  // row sums Z[h]
    __shared__ float w_lds[4];

    const int t = threadIdx.x;
    const int bid = (int)blockIdx.x;
    const int n = (bid < 256) ? (NM1 - bid) : (bid - 255);       // CU-aware pairing
    const int ksteps = (n + 63) >> 6;
    const int wv = t >> 6, lane = t & 63, half = lane >> 5, r = lane & 31;

    if (t < 64) z_lds[t] = 0.f;
    // W table from plusT: entry (tile, mm, hh) = plus[n][tile*32+mm*16+hh*4 +
    // {0..3}] ++ [+8..+11] (k-order sigma of the reduce-MFMA A-fragment)
    if (t < 128) {
        const int tile = t >> 2, mm = (t >> 1) & 1, hh = t & 1;
        const float* src = plusT + (size_t)n * NM + tile * 32 + mm * 16 + hh * 4;
        f32x4 v0 = *(const f32x4*)(src);
        f32x4 v1 = *(const f32x4*)(src + 8);
        unsigned short* dst = plusbf + (size_t)((tile * 2 + mm) * 2 + hh) * 8;
        dst[0] = f2bf(v0.x); dst[1] = f2bf(v0.y); dst[2] = f2bf(v0.z); dst[3] = f2bf(v0.w);
        dst[4] = f2bf(v1.x); dst[5] = f2bf(v1.y); dst[6] = f2bf(v1.z); dst[7] = f2bf(v1.w);
    }

    // ================= phase 1: hat_phi tile (256 b x 64 h) =================
    const int eh = t >> 2, ei = (t & 3) * 16;
    const float* arow = Al + ((size_t)n * NH + eh) * NPOS + ei;
    const unsigned short* s0 = seq_bf + (size_t)(wv * 64 + r) * NPOS;        // bs=0
    const unsigned short* s1 = seq_bf + (size_t)(wv * 64 + 32 + r) * NPOS;   // bs=1

    f32x16 acc00, acc01, acc10, acc11;
#pragma unroll
    for (int i = 0; i < 16; i++) { acc00[i] = 0.f; acc01[i] = 0.f; acc10[i] = 0.f; acc11[i] = 0.f; }

    f32x4 ea[4];
    bf16x8 sc0[4], sc1[4], sn0[4], sn1[4];
#pragma unroll
    for (int g = 0; g < 4; g++) ea[g] = *(const f32x4*)(arow + g * 4);
#pragma unroll
    for (int kq = 0; kq < 4; kq++) {
        sc0[kq] = *(const bf16x8*)(s0 + kq * 16 + half * 8);
        sc1[kq] = *(const bf16x8*)(s1 + kq * 16 + half * 8);
    }
    __syncthreads();   // z_lds init + W table staged

    for (int kk = 0; kk < ksteps; kk++) {
        const int k0 = kk * 64;
        unsigned short* ebuf = (unsigned short*)e_lds[kk & 1];
        // 1. exp + stage E tile from regs (masked), accumulate Z
        {
            float zp = 0.f;
            unsigned short* ep = ebuf + eh * 72 + ei;
#pragma unroll
            for (int g = 0; g < 4; g++) {
                int i0 = k0 + ei + g * 4;
                float e0 = (i0 + 0 < n) ? __expf(ea[g].x) : 0.f;
                float e1 = (i0 + 1 < n) ? __expf(ea[g].y) : 0.f;
                float e2 = (i0 + 2 < n) ? __expf(ea[g].z) : 0.f;
                float e3 = (i0 + 3 < n) ? __expf(ea[g].w) : 0.f;
                zp += (e0 + e1) + (e2 + e3);
                int2 o; o.x = pack2(f2bf(e0), f2bf(e1)); o.y = pack2(f2bf(e2), f2bf(e3));
                *(int2*)(ep + g * 4) = o;
            }
            zp += __shfl_xor(zp, 1);
            zp += __shfl_xor(zp, 2);
            if ((t & 3) == 0) z_lds[eh] += zp;
        }
        // 2. prefetch k+1 (A row + S fragments) — stays in flight across barrier
        if (kk + 1 < ksteps) {
#pragma unroll
            for (int g = 0; g < 4; g++) ea[g] = *(const f32x4*)(arow + k0 + 64 + g * 4);
#pragma unroll
            for (int kq = 0; kq < 4; kq++) {
                sn0[kq] = *(const bf16x8*)(s0 + k0 + 64 + kq * 16 + half * 8);
                sn1[kq] = *(const bf16x8*)(s1 + k0 + 64 + kq * 16 + half * 8);
            }
        }
        // 3. LDS-only fence + raw barrier (global prefetches NOT drained)
        asm volatile("s_waitcnt lgkmcnt(0)" ::: "memory");
        __builtin_amdgcn_s_barrier();
        asm volatile("" ::: "memory");
        // 4. MFMA: D[b][h] += S[b,i] * E[h,i]
        {
            const unsigned short* sB0 = ebuf + r * 72;
            const unsigned short* sB1 = sB0 + 32 * 72;
#pragma unroll
            for (int kq = 0; kq < 4; kq++) {
                const int ko = kq * 16 + half * 8;
                bf16x8 B0 = *(const bf16x8*)(sB0 + ko);
                bf16x8 B1 = *(const bf16x8*)(sB1 + ko);
                acc00 = __builtin_amdgcn_mfma_f32_32x32x16_bf16(sc0[kq], B0, acc00, 0, 0, 0);
                acc01 = __builtin_amdgcn_mfma_f32_32x32x16_bf16(sc0[kq], B1, acc01, 0, 0, 0);
                acc10 = __builtin_amdgcn_mfma_f32_32x32x16_bf16(sc1[kq], B0, acc10, 0, 0, 0);
                acc11 = __builtin_amdgcn_mfma_f32_32x32x16_bf16(sc1[kq], B1, acc11, 0, 0, 0);
            }
        }
        // 5. rotate S fragments
        if (kk + 1 < ksteps) {
#pragma unroll
            for (int kq = 0; kq < 4; kq++) { sc0[kq] = sn0[kq]; sc1[kq] = sn1[kq]; }
        }
    }
    // epilogue: scale by 1/Z[h], write q tile into q_lds (wave-own rows; no
    // barrier needed before the same wave reads them back in phase 2).
    {
        float rz0 = 1.0f / z_lds[r];
        float rz1 = 1.0f / z_lds[32 + r];
#pragma unroll
        for (int reg = 0; reg < 16; reg++) {
            int row = (reg & 3) + 8 * (reg >> 2) + 4 * half;
            q_lds[(wv * 64 + row) * 72 + r]            = f2bf(acc00[reg] * rz0);
            q_lds[(wv * 64 + row) * 72 + 32 + r]       = f2bf(acc01[reg] * rz1);
            q_lds[(wv * 64 + 32 + row) * 72 + r]       = f2bf(acc10[reg] * rz0);
            q_lds[(wv * 64 + 32 + row) * 72 + 32 + r]  = f2bf(acc11[reg] * rz1);
        }
    }

    // ================= phase 2: retrieval softmax (MFMA-reduced) ============
    bf16x8 p[4], pn[4];
    p2_loadF(p, phimuF, 0, lane);              // coalesced; issue first
    bf16x8 q0[4], q1[4];
#pragma unroll
    for (int kq = 0; kq < 4; kq++) {
        q0[kq] = *(const bf16x8*)(q_lds + (wv * 64 + r) * 72 + kq * 16 + half * 8);
        q1[kq] = *(const bf16x8*)(q_lds + (wv * 64 + 32 + r) * 72 + kq * 16 + half * 8);
    }
    f32x16 zacc, accD0, accD1;
#pragma unroll
    for (int i = 0; i < 16; i++) { zacc[i] = 0.f; accD0[i] = 0.f; accD1[i] = 0.f; }

    // per-lane W-column constants: col 0 = ones, col 1 = plus, others 0
    const unsigned onespat = (r == 0) ? 0x3F803F80u : 0u;
    const unsigned pmask   = (r == 1) ? 0xFFFFFFFFu : 0u;

    for (int it = 0; it < 32; ++it) {
        if (it < 31) p2_loadF(pn, phimuF, it + 1, lane);   // prefetch, no barrier
        // score MFMAs: a0 (b 0..31), a1 (b 32..63)
        f32x16 a0, a1;
        a0 = __builtin_amdgcn_mfma_f32_32x32x16_bf16(p[0], q0[0], zacc, 0, 0, 0);
        a1 = __builtin_amdgcn_mfma_f32_32x32x16_bf16(p[0], q1[0], zacc, 0, 0, 0);
#pragma unroll
        for (int kq = 1; kq < 4; kq++) {
            a0 = __builtin_amdgcn_mfma_f32_32x32x16_bf16(p[kq], q0[kq], a0, 0, 0, 0);
            a1 = __builtin_amdgcn_mfma_f32_32x32x16_bf16(p[kq], q1[kq], a1, 0, 0, 0);
        }
        // W fragments for this tile (broadcast LDS reads; k-order = sigma)
        i32x4 w1r = *(const i32x4*)(plusbf + (size_t)(4 * it + half) * 8);
        i32x4 w2r = *(const i32x4*)(plusbf + (size_t)(4 * it + 2 + half) * 8);
        i32x4 W1, W2;
        W1.x = onespat | (w1r.x & pmask); W1.y = onespat | (w1r.y & pmask);
        W1.z = onespat | (w1r.z & pmask); W1.w = onespat | (w1r.w & pmask);
        W2.x = onespat | (w2r.x & pmask); W2.y = onespat | (w2r.y & pmask);
        W2.z = onespat | (w2r.z & pmask); W2.w = onespat | (w2r.w & pmask);
        // exp -> bf16 A-fragments, reduce-MFMA into accD (col0=den, col1=num)
        {
            float e00 = EXP2F(a0[0]),  e01 = EXP2F(a0[1]),  e02 = EXP2F(a0[2]),  e03 = EXP2F(a0[3]);
            float e04 = EXP2F(a0[4]),  e05 = EXP2F(a0[5]),  e06 = EXP2F(a0[6]),  e07 = EXP2F(a0[7]);
            float e08 = EXP2F(a0[8]),  e09 = EXP2F(a0[9]),  e10 = EXP2F(a0[10]), e11 = EXP2F(a0[11]);
            float e12 = EXP2F(a0[12]), e13 = EXP2F(a0[13]), e14 = EXP2F(a0[14]), e15 = EXP2F(a0[15]);
            i32x4 A1, A2;
            A1.x = cvtpk(e00, e01); A1.y = cvtpk(e02, e03); A1.z = cvtpk(e04, e05); A1.w = cvtpk(e06, e07);
            A2.x = cvtpk(e08, e09); A2.y = cvtpk(e10, e11); A2.z = cvtpk(e12, e13); A2.w = cvtpk(e14, e15);
            accD0 = __builtin_amdgcn_mfma_f32_32x32x16_bf16(*(bf16x8*)&A1, *(bf16x8*)&W1, accD0, 0, 0, 0);
            accD0 = __builtin_amdgcn_mfma_f32_32x32x16_bf16(*(bf16x8*)&A2, *(bf16x8*)&W2, accD0, 0, 0, 0);
        }
        {
            float e00 = EXP2F(a1[0]),  e01 = EXP2F(a1[1]),  e02 = EXP2F(a1[2]),  e03 = EXP2F(a1[3]);
            float e04 = EXP2F(a1[4]),  e05 = EXP2F(a1[5]),  e06 = EXP2F(a1[6]),  e07 = EXP2F(a1[7]);
            float e08 = EXP2F(a1[8]),  e09 = EXP2F(a1[9]),  e10 = EXP2F(a1[10]), e11 = EXP2F(a1[11]);
            float e12 = EXP2F(a1[12]), e13 = EXP2F(a1[13]), e14 = EXP2F(a1[14]), e15 = EXP2F(a1[15]);
            i32x4 A1, A2;
            A1.x = cvtpk(e00, e01); A1.y = cvtpk(e02, e03); A1.z = cvtpk(e04, e05); A1.w = cvtpk(e06, e07);
            A2.x = cvtpk(e08, e09); A2.y = cvtpk(e10, e11); A2.z = cvtpk(e12, e13); A2.w = cvtpk(e14, e15);
            accD1 = __builtin_amdgcn_mfma_f32_32x32x16_bf16(*(bf16x8*)&A1, *(bf16x8*)&W1, accD1, 0, 0, 0);
            accD1 = __builtin_amdgcn_mfma_f32_32x32x16_bf16(*(bf16x8*)&A2, *(bf16x8*)&W2, accD1, 0, 0, 0);
        }
        if (it < 31) {
#pragma unroll
            for (int kq = 0; kq < 4; kq++) p[kq] = pn[kq];
        }
    }

    // formal fence: all waves done reading e_lds (phase 1) before reuse below
    __syncthreads();
    // accD layout: col r==0 holds den[b=rowmap], col r==1 holds num.
    float* dsum = (float*)e_lds;          // 256 floats (e_lds dead after phase 1)
    float* nsum = dsum + 256;
    if (r < 2) {
        float* dst = (r == 0) ? dsum : nsum;
#pragma unroll
        for (int reg = 0; reg < 16; reg++) {
            int row = (reg & 3) + 8 * (reg >> 2) + 4 * half;
            dst[wv * 64 + row]      = accD0[reg];
            dst[wv * 64 + 32 + row] = accD1[reg];
        }
    }
    __syncthreads();
    // BCE for b = t
    {
        float dd = dsum[t], nn = nsum[t];
        float p2 = nn / dd;
        p2 = fminf(fmaxf(p2, 1e-6f), 1.0f - 1e-6f);
        float tg = seq[(size_t)t * NPOS + n];
        float bce = (tg > 0.f) ? -logf(p2) : -logf(1.0f - p2);
#pragma unroll
        for (int o = 32; o; o >>= 1) bce += __shfl_xor(bce, o);
        if (lane == 0) w_lds[wv] = bce;
    }
    __syncthreads();
    if (t == 0)
        atomicAdd(out, (w_lds[0] + w_lds[1] + w_lds[2] + w_lds[3]) * (1.0f / 130816.0f));
}

extern "C" void kernel_launch(void* const* d_in, const int* in_sizes, int n_in,
                              void* d_out, int out_size, void* d_ws, size_t ws_size,
                              hipStream_t stream) {
    const float* seq = (const float*)d_in[0];  // (B,N)
    const float* mem = (const float*)d_in[1];  // (M,N)
    const float* Al  = (const float*)d_in[2];  // (N,H,N)
    const float* Bl  = (const float*)d_in[3];  // (H,N)

    char* ws = (char*)d_ws;
    unsigned short* seq_bf = (unsigned short*)(ws + 0);          // 256 KB
    float*          BnT    = (float*)(ws + 262144);              // 128 KB (N,H)
    unsigned short* phimuF = (unsigned short*)(ws + 393216);     // 128 KB fragment layout
    float*          plusT  = (float*)(ws + 524288);              // 2 MB (N,M)
    float*          outp   = (float*)d_out;                      // total 2.6 MB (proven R0-R3)

    kA_prep<<<272, 256, 0, stream>>>(seq, Bl, mem, seq_bf, BnT, plusT, outp);
    k1b_phimu<<<128, 256, 0, stream>>>(BnT, mem, phimuF);
    k23_fused<<<511, 256, 0, stream>>>(Al, seq_bf, phimuF, plusT, seq, outp);
}